// Round 2
// baseline (458.231 us; speedup 1.0000x reference)
//
#include <hip/hip_runtime.h>
#include <math.h>

#define B_ 2
#define H_ 16
#define S_ 2048
#define CTX_ 1024
#define VD_ 288
#define VD2_ 576
#define FFN_ 512
#define FFNH_ 256
#define NH1_ 17
#define EPSILON_ 0.066f
#define LN_EPS_ 1e-5f
#define TPB_ 8                    // tokens per block
#define NBLK_ (B_ * S_ / TPB_)    // 512 blocks

__device__ __forceinline__ float gelu_exact(float x) {
    return 0.5f * x * (1.0f + erff(x * 0.70710678118654752440f));
}

__device__ __forceinline__ void fma8(float* a, float w, const float4& lo, const float4& hi) {
    a[0] += w * lo.x; a[1] += w * lo.y; a[2] += w * lo.z; a[3] += w * lo.w;
    a[4] += w * hi.x; a[5] += w * hi.y; a[6] += w * hi.z; a[7] += w * hi.w;
}

__device__ __forceinline__ void store8_gelu(float* dst, const float* a, float b) {
    float4 o0 = make_float4(gelu_exact(a[0] + b), gelu_exact(a[1] + b),
                            gelu_exact(a[2] + b), gelu_exact(a[3] + b));
    float4 o1 = make_float4(gelu_exact(a[4] + b), gelu_exact(a[5] + b),
                            gelu_exact(a[6] + b), gelu_exact(a[7] + b));
    *(float4*)&dst[0] = o0;
    *(float4*)&dst[4] = o1;
}

__global__ void zero_counts_kernel(int* __restrict__ counts) {
    int i = blockIdx.x * blockDim.x + threadIdx.x;
    if (i < CTX_) counts[i] = 0;
}

__global__ void count_tokens_kernel(const int* __restrict__ ids, int* __restrict__ counts) {
    int i = blockIdx.x * blockDim.x + threadIdx.x;
    if (i < B_ * S_) atomicAdd(&counts[ids[i]], 1);
}

// 512 threads = 8 waves. Waves (p, p+4) cooperate on token pair p (tokens
// 2p, 2p+1): each takes half the K range with the ORIGINAL 9-wide/4-wide
// independent-load inner loop (preserves memory-level parallelism), then the
// halves merge through LDS scratch. Doubles waves/SIMD (2 -> 4) and halves
// the per-wave dependent-latency chain without changing weight bytes/token.
__global__ __launch_bounds__(512) void token_mlp_kernel(
    const int* __restrict__ ids, const int* __restrict__ counts,
    const float* __restrict__ embW,
    const float* __restrict__ lnvw, const float* __restrict__ lnvb,
    const float* __restrict__ pW1, const float* __restrict__ pb1,
    const float* __restrict__ pW2, const float* __restrict__ pb2,
    const float* __restrict__ lncw, const float* __restrict__ lncb,
    const float* __restrict__ fW1, const float* __restrict__ fb1,
    const float* __restrict__ fW2, const float* __restrict__ fb2,
    const float* __restrict__ fW3, const float* __restrict__ fb3,
    float* __restrict__ wout)
{
    // activations transposed: [dim][token]; 8-token row = 32B contiguous.
    __shared__ __align__(16) float va[VD_][TPB_];      //  9.2 KB
    __shared__ __align__(16) float ha[VD2_][TPB_];     // 18.4 KB
    __shared__ __align__(16) float part[VD2_][TPB_];   // 18.4 KB (k-split partials)
    __shared__ __align__(16) float comb17[NH1_][TPB_]; //  0.5 KB
    __shared__ __align__(16) float h2a[FFN_][TPB_];    // 16.4 KB
    __shared__ __align__(16) float h3a[FFNH_][TPB_];   //  8.2 KB
    // total ~71.2 KB -> 2 blocks/CU (grid-limited at 2 anyway)

    const int tid  = threadIdx.x;
    const int tok0 = blockIdx.x * TPB_;
    const int wid  = tid >> 6;     // wave 0..7
    const int cthr = tid & 63;
    const int pair = wid & 3;      // token pair 0..3
    const int half = wid >> 2;     // k-half 0/1
    const int t0   = pair * 2;

    // ---- phase 0: embedding gather + LayerNorm(288); one wave per token ----
    {
        const int w  = wid;          // token index 0..7
        const int l  = cthr;
        const int id = ids[tok0 + w];
        float x[5];
        float s = 0.f, sq = 0.f;
        #pragma unroll
        for (int r = 0; r < 4; ++r) {
            float xv = embW[id * VD_ + l + 64 * r];
            x[r] = xv; s += xv; sq += xv * xv;
        }
        x[4] = 0.f;
        if (l < 32) {
            float xv = embW[id * VD_ + 256 + l];
            x[4] = xv; s += xv; sq += xv * xv;
        }
        #pragma unroll
        for (int m = 32; m >= 1; m >>= 1) {
            s  += __shfl_xor(s,  m, 64);
            sq += __shfl_xor(sq, m, 64);
        }
        float mu   = s * (1.f / VD_);
        float var  = sq * (1.f / VD_) - mu * mu;
        float rstd = rsqrtf(var + LN_EPS_);
        #pragma unroll
        for (int r = 0; r < 4; ++r) {
            int i = l + 64 * r;
            va[i][w] = (x[r] - mu) * rstd * lnvw[i] + lnvb[i];
        }
        if (l < 32) {
            int i = 256 + l;
            va[i][w] = (x[4] - mu) * rstd * lnvw[i] + lnvb[i];
        }
    }
    __syncthreads();

    // ---- phase 1: ha = gelu(va @ pW1 + pb1)  [288 -> 576], k split in 2 ----
    {
        float2 acc[9];
        #pragma unroll
        for (int c = 0; c < 9; ++c) acc[c] = make_float2(0.f, 0.f);
        const int k0 = half * 144;
        for (int k = k0; k < k0 + 144; ++k) {
            float2 v = *(const float2*)&va[k][t0];
            const float* wrow = &pW1[k * VD2_ + cthr];
            #pragma unroll
            for (int c = 0; c < 9; ++c) {
                float w = wrow[64 * c];
                acc[c].x += w * v.x; acc[c].y += w * v.y;
            }
        }
        if (half) {
            #pragma unroll
            for (int c = 0; c < 9; ++c)
                *(float2*)&part[cthr + 64 * c][t0] = acc[c];
        }
        __syncthreads();
        if (!half) {
            #pragma unroll
            for (int c = 0; c < 9; ++c) {
                int col = cthr + 64 * c;
                float2 pp = *(const float2*)&part[col][t0];
                float b = pb1[col];
                float2 o = make_float2(gelu_exact(acc[c].x + pp.x + b),
                                       gelu_exact(acc[c].y + pp.y + b));
                *(float2*)&ha[col][t0] = o;
            }
        }
    }
    __syncthreads();

    // ---- phase 2: valence = tanh(ha @ pW2 + pb2) [576 -> 16] + occ; k split 8-way ----
    {
        const int col = cthr & 15;
        const int ks  = half * 4 + (cthr >> 4);   // 0..7, 72 k each
        float2 acc = make_float2(0.f, 0.f);
        for (int k = ks * 72; k < ks * 72 + 72; ++k) {
            float2 v = *(const float2*)&ha[k][t0];
            float w = pW2[k * H_ + col];
            acc.x += w * v.x; acc.y += w * v.y;
        }
        acc.x += __shfl_xor(acc.x, 16, 64); acc.y += __shfl_xor(acc.y, 16, 64);
        acc.x += __shfl_xor(acc.x, 32, 64); acc.y += __shfl_xor(acc.y, 32, 64);
        if (half && cthr < 16)
            *(float2*)&part[col][t0] = acc;
        __syncthreads();
        if (!half) {
            if (cthr < 16) {
                float2 pp = *(const float2*)&part[col][t0];
                float b = pb2[col];
                float2 o = make_float2(tanhf(acc.x + pp.x + b),
                                       tanhf(acc.y + pp.y + b));
                *(float2*)&comb17[1 + col][t0] = o;
            }
            if (cthr == 16) {
                #pragma unroll
                for (int j = 0; j < 2; ++j) {
                    int t = t0 + j;
                    int id = ids[tok0 + t];
                    float c = (float)counts[id];
                    if (c < 1.f) c = 1.f;
                    comb17[0][t] = log1pf(c);
                }
            }
        }
    }
    __syncthreads();

    // ---- phase 3: LayerNorm(17), one thread per token ----
    if (tid < TPB_) {
        float vals[NH1_];
        float s = 0.f;
        #pragma unroll
        for (int i = 0; i < NH1_; ++i) { vals[i] = comb17[i][tid]; s += vals[i]; }
        float mu = s / NH1_;
        float vq = 0.f;
        #pragma unroll
        for (int i = 0; i < NH1_; ++i) { float d = vals[i] - mu; vq += d * d; }
        float r = rsqrtf(vq / NH1_ + LN_EPS_);
        #pragma unroll
        for (int i = 0; i < NH1_; ++i)
            comb17[i][tid] = (vals[i] - mu) * r * lncw[i] + lncb[i];
    }
    __syncthreads();

    // ---- phase 4: h2 = gelu(comb @ fW1 + fb1) [17 -> 512] ----
    // 512 cols / 512 threads, fully unrolled 17-iter loop: 17 independent
    // loads in flight, perfectly balanced.
    {
        float a[8];
        #pragma unroll
        for (int j = 0; j < 8; ++j) a[j] = 0.f;
        #pragma unroll
        for (int k = 0; k < NH1_; ++k) {
            const float4 vlo = *(const float4*)&comb17[k][0];
            const float4 vhi = *(const float4*)&comb17[k][4];
            fma8(a, fW1[k * FFN_ + tid], vlo, vhi);
        }
        store8_gelu(&h2a[tid][0], a, fb1[tid]);
    }
    __syncthreads();

    // ---- phase 5: h3 = gelu(h2 @ fW2 + fb2) [512 -> 256], k split in 2 ----
    {
        float2 acc[4];
        #pragma unroll
        for (int c = 0; c < 4; ++c) acc[c] = make_float2(0.f, 0.f);
        const int k0 = half * 256;
        for (int k = k0; k < k0 + 256; ++k) {
            float2 v = *(const float2*)&h2a[k][t0];
            const float* wrow = &fW2[k * FFNH_ + cthr];
            #pragma unroll
            for (int c = 0; c < 4; ++c) {
                float w = wrow[64 * c];
                acc[c].x += w * v.x; acc[c].y += w * v.y;
            }
        }
        if (half) {
            #pragma unroll
            for (int c = 0; c < 4; ++c)
                *(float2*)&part[cthr + 64 * c][t0] = acc[c];
        }
        __syncthreads();
        if (!half) {
            #pragma unroll
            for (int c = 0; c < 4; ++c) {
                int col = cthr + 64 * c;
                float2 pp = *(const float2*)&part[col][t0];
                float b = fb2[col];
                float2 o = make_float2(gelu_exact(acc[c].x + pp.x + b),
                                       gelu_exact(acc[c].y + pp.y + b));
                *(float2*)&h3a[col][t0] = o;
            }
        }
    }
    __syncthreads();

    // ---- phase 6: mod = tanh(h3 . fW3 + fb3); one wave per token ----
    {
        const int tt = wid;
        const int l  = cthr;
        float acc = 0.f;
        #pragma unroll
        for (int r = 0; r < FFNH_ / 64; ++r) {
            int k = l + 64 * r;
            acc += h3a[k][tt] * fW3[k];
        }
        #pragma unroll
        for (int m = 32; m >= 1; m >>= 1) acc += __shfl_xor(acc, m, 64);
        if (l == 0) {
            float mod = tanhf(acc + fb3[0]);
            wout[tok0 + tt] = 1.0f + EPSILON_ * mod;
        }
    }
}

__global__ __launch_bounds__(256) void scale_kernel(
    const float4* __restrict__ in, const float* __restrict__ w,
    float4* __restrict__ out, long total4)
{
    long i = (long)blockIdx.x * blockDim.x + threadIdx.x;
    const long stride = (long)gridDim.x * blockDim.x;
    for (; i < total4; i += stride) {
        long row = i >> 9;                 // / (S/4=512)  -> flat row in [B*H*S)
        int b = (int)(row >> 15);          // / (H*S = 32768)
        int s = (int)(row & (S_ - 1));
        float ww = w[b * S_ + s];
        float4 x = in[i];
        x.x *= ww; x.y *= ww; x.z *= ww; x.w *= ww;
        out[i] = x;
    }
}

extern "C" void kernel_launch(void* const* d_in, const int* in_sizes, int n_in,
                              void* d_out, int out_size, void* d_ws, size_t ws_size,
                              hipStream_t stream) {
    const float* scores = (const float*)d_in[0];
    const int*   ids    = (const int*)  d_in[1];
    const float* embW   = (const float*)d_in[2];
    const float* lnvw   = (const float*)d_in[3];
    const float* lnvb   = (const float*)d_in[4];
    const float* pW1    = (const float*)d_in[5];
    const float* pb1    = (const float*)d_in[6];
    const float* pW2    = (const float*)d_in[7];
    const float* pb2    = (const float*)d_in[8];
    const float* lncw   = (const float*)d_in[9];
    const float* lncb   = (const float*)d_in[10];
    const float* fW1    = (const float*)d_in[11];
    const float* fb1    = (const float*)d_in[12];
    const float* fW2    = (const float*)d_in[13];
    const float* fb2    = (const float*)d_in[14];
    const float* fW3    = (const float*)d_in[15];
    const float* fb3    = (const float*)d_in[16];

    int*   counts = (int*)d_ws;
    float* wout   = (float*)((char*)d_ws + CTX_ * sizeof(int));

    zero_counts_kernel<<<(CTX_ + 255) / 256, 256, 0, stream>>>(counts);
    count_tokens_kernel<<<(B_ * S_ + 255) / 256, 256, 0, stream>>>(ids, counts);
    token_mlp_kernel<<<NBLK_, 512, 0, stream>>>(
        ids, counts, embW, lnvw, lnvb, pW1, pb1, pW2, pb2,
        lncw, lncb, fW1, fb1, fW2, fb2, fW3, fb3, wout);

    long total4 = (long)B_ * H_ * S_ * S_ / 4;   // 33,554,432 float4s
    scale_kernel<<<2048, 256, 0, stream>>>(
        (const float4*)scores, wout, (float4*)d_out, total4);
}

// Round 4
// 311.653 us; speedup vs baseline: 1.4703x; 1.4703x over previous
//
#include <hip/hip_runtime.h>
#include <math.h>

#define B_ 2
#define H_ 16
#define S_ 2048
#define CTX_ 1024
#define VD_ 288
#define VD2_ 576
#define FFN_ 512
#define FFNH_ 256
#define NH1_ 17
#define EPSILON_ 0.066f
#define LN_EPS_ 1e-5f
#define TPB_ 16                   // tokens per block (was 8)
#define NBLK_ (B_ * S_ / TPB_)    // 256 blocks

typedef float vfloat4 __attribute__((ext_vector_type(4)));  // native vec for NT builtins

__device__ __forceinline__ float gelu_exact(float x) {
    return 0.5f * x * (1.0f + erff(x * 0.70710678118654752440f));
}

// one-block fused histogram: zero + count + writeback (replaces 2 kernels)
__global__ __launch_bounds__(1024) void count_kernel(
    const int* __restrict__ ids, int* __restrict__ counts)
{
    __shared__ int hist[CTX_];
    const int t = threadIdx.x;          // 1024 threads == CTX_
    hist[t] = 0;
    __syncthreads();
    #pragma unroll
    for (int r = 0; r < (B_ * S_) / 1024; ++r)
        atomicAdd(&hist[ids[t + 1024 * r]], 1);
    __syncthreads();
    counts[t] = hist[t];
}

// 512 threads = 8 waves, 16 tokens. Wave w owns token pair (2w, 2w+1) with
// the EXACT round-0 per-wave inner loops (9-wide / 8-wide / 4-wide
// independent-load fan, float2 LDS broadcasts). Only the block got fatter:
// half the blocks -> half the per-CU weight traffic through L1/L2.
__global__ __launch_bounds__(512) void token_mlp_kernel(
    const int* __restrict__ ids, const int* __restrict__ counts,
    const float* __restrict__ embW,
    const float* __restrict__ lnvw, const float* __restrict__ lnvb,
    const float* __restrict__ pW1, const float* __restrict__ pb1,
    const float* __restrict__ pW2, const float* __restrict__ pb2,
    const float* __restrict__ lncw, const float* __restrict__ lncb,
    const float* __restrict__ fW1, const float* __restrict__ fb1,
    const float* __restrict__ fW2, const float* __restrict__ fb2,
    const float* __restrict__ fW3, const float* __restrict__ fb3,
    float* __restrict__ wout)
{
    // activations transposed: [dim][token]
    __shared__ __align__(16) float va[VD_][TPB_];      // 18.4 KB
    __shared__ __align__(16) float ha[VD2_][TPB_];     // 36.9 KB
    __shared__ __align__(16) float comb17[NH1_][TPB_]; //  1.1 KB
    __shared__ __align__(16) float h2a[FFN_][TPB_];    // 32.8 KB
    __shared__ __align__(16) float h3a[FFNH_][TPB_];   // 16.4 KB
    // total 105.6 KB -> 1 block/CU, 8 waves = 2 waves/SIMD (same as round 0)

    const int tid  = threadIdx.x;
    const int tok0 = blockIdx.x * TPB_;
    const int wid  = tid >> 6;   // wave 0..7 -> token pair
    const int cthr = tid & 63;
    const int t0   = wid * 2;

    // ---- phase 0: embedding gather + LayerNorm(288); 32 threads/token ----
    {
        const int tt = tid >> 5;      // 0..15
        const int l  = tid & 31;
        const int id = ids[tok0 + tt];
        float x[9];
        float s = 0.f, sq = 0.f;
        #pragma unroll
        for (int r = 0; r < 9; ++r) {
            float xv = embW[id * VD_ + l + 32 * r];
            x[r] = xv; s += xv; sq += xv * xv;
        }
        #pragma unroll
        for (int m = 16; m >= 1; m >>= 1) {
            s  += __shfl_xor(s,  m, 64);
            sq += __shfl_xor(sq, m, 64);
        }
        float mu   = s * (1.f / VD_);
        float var  = sq * (1.f / VD_) - mu * mu;
        float rstd = rsqrtf(var + LN_EPS_);
        #pragma unroll
        for (int r = 0; r < 9; ++r) {
            int i = l + 32 * r;
            va[i][tt] = (x[r] - mu) * rstd * lnvw[i] + lnvb[i];
        }
    }
    __syncthreads();

    // ---- phase 1: ha = gelu(va @ pW1 + pb1)  [288 -> 576] ----
    {
        float2 acc[9];
        #pragma unroll
        for (int c = 0; c < 9; ++c) acc[c] = make_float2(0.f, 0.f);
        for (int k = 0; k < VD_; ++k) {
            float2 v = *(const float2*)&va[k][t0];
            const float* wrow = &pW1[k * VD2_ + cthr];
            #pragma unroll
            for (int c = 0; c < 9; ++c) {
                float w = wrow[64 * c];
                acc[c].x += w * v.x; acc[c].y += w * v.y;
            }
        }
        #pragma unroll
        for (int c = 0; c < 9; ++c) {
            int col = cthr + 64 * c;
            float b = pb1[col];
            float2 o = make_float2(gelu_exact(acc[c].x + b), gelu_exact(acc[c].y + b));
            *(float2*)&ha[col][t0] = o;
        }
    }
    __syncthreads();

    // ---- phase 2: valence = tanh(ha @ pW2 + pb2) [576 -> 16] + occ ----
    {
        const int col = cthr & 15;
        const int ks  = cthr >> 4;      // 4-way K split (144 each)
        float2 acc = make_float2(0.f, 0.f);
        for (int k = ks * 144; k < ks * 144 + 144; ++k) {
            float2 v = *(const float2*)&ha[k][t0];
            float w = pW2[k * H_ + col];
            acc.x += w * v.x; acc.y += w * v.y;
        }
        acc.x += __shfl_xor(acc.x, 16, 64); acc.y += __shfl_xor(acc.y, 16, 64);
        acc.x += __shfl_xor(acc.x, 32, 64); acc.y += __shfl_xor(acc.y, 32, 64);
        if (cthr < 16) {
            float b = pb2[col];
            float2 o = make_float2(tanhf(acc.x + b), tanhf(acc.y + b));
            *(float2*)&comb17[1 + col][t0] = o;
        }
        if (cthr == 16) {
            #pragma unroll
            for (int j = 0; j < 2; ++j) {
                int t = t0 + j;
                int id = ids[tok0 + t];
                float c = (float)counts[id];
                if (c < 1.f) c = 1.f;
                comb17[0][t] = log1pf(c);
            }
        }
    }
    __syncthreads();

    // ---- phase 3: LayerNorm(17), one thread per token ----
    if (tid < TPB_) {
        float vals[NH1_];
        float s = 0.f;
        #pragma unroll
        for (int i = 0; i < NH1_; ++i) { vals[i] = comb17[i][tid]; s += vals[i]; }
        float mu = s / NH1_;
        float vq = 0.f;
        #pragma unroll
        for (int i = 0; i < NH1_; ++i) { float d = vals[i] - mu; vq += d * d; }
        float r = rsqrtf(vq / NH1_ + LN_EPS_);
        #pragma unroll
        for (int i = 0; i < NH1_; ++i)
            comb17[i][tid] = (vals[i] - mu) * r * lncw[i] + lncb[i];
    }
    __syncthreads();

    // ---- phase 4: h2 = gelu(comb @ fW1 + fb1) [17 -> 512] ----
    {
        float2 acc[8];
        #pragma unroll
        for (int c = 0; c < 8; ++c) acc[c] = make_float2(0.f, 0.f);
        #pragma unroll
        for (int k = 0; k < NH1_; ++k) {
            float2 v = *(const float2*)&comb17[k][t0];
            const float* wrow = &fW1[k * FFN_ + cthr];
            #pragma unroll
            for (int c = 0; c < 8; ++c) {
                float w = wrow[64 * c];
                acc[c].x += w * v.x; acc[c].y += w * v.y;
            }
        }
        #pragma unroll
        for (int c = 0; c < 8; ++c) {
            int col = cthr + 64 * c;
            float b = fb1[col];
            float2 o = make_float2(gelu_exact(acc[c].x + b), gelu_exact(acc[c].y + b));
            *(float2*)&h2a[col][t0] = o;
        }
    }
    __syncthreads();

    // ---- phase 5: h3 = gelu(h2 @ fW2 + fb2) [512 -> 256] ----
    {
        float2 acc[4];
        #pragma unroll
        for (int c = 0; c < 4; ++c) acc[c] = make_float2(0.f, 0.f);
        for (int k = 0; k < FFN_; ++k) {
            float2 v = *(const float2*)&h2a[k][t0];
            const float* wrow = &fW2[k * FFNH_ + cthr];
            #pragma unroll
            for (int c = 0; c < 4; ++c) {
                float w = wrow[64 * c];
                acc[c].x += w * v.x; acc[c].y += w * v.y;
            }
        }
        #pragma unroll
        for (int c = 0; c < 4; ++c) {
            int col = cthr + 64 * c;
            float b = fb2[col];
            float2 o = make_float2(gelu_exact(acc[c].x + b), gelu_exact(acc[c].y + b));
            *(float2*)&h3a[col][t0] = o;
        }
    }
    __syncthreads();

    // ---- phase 6: mod = tanh(h3 . fW3 + fb3); 32 threads/token ----
    {
        const int tt = tid >> 5;      // 0..15
        const int l  = tid & 31;
        float acc = 0.f;
        #pragma unroll
        for (int r = 0; r < FFNH_ / 32; ++r) {
            int k = l + 32 * r;
            acc += h3a[k][tt] * fW3[k];
        }
        #pragma unroll
        for (int m = 16; m >= 1; m >>= 1) acc += __shfl_xor(acc, m, 64);
        if (l == 0) {
            float mod = tanhf(acc + fb3[0]);
            wout[tok0 + tt] = 1.0f + EPSILON_ * mod;
        }
    }
}

__global__ __launch_bounds__(256) void scale_kernel(
    const vfloat4* __restrict__ in, const float* __restrict__ w,
    vfloat4* __restrict__ out, long total4)
{
    long i = (long)blockIdx.x * blockDim.x + threadIdx.x;
    const long stride = (long)gridDim.x * blockDim.x;
    for (; i < total4; i += stride) {
        long row = i >> 9;                 // / (S/4=512)  -> flat row in [B*H*S)
        int b = (int)(row >> 15);          // / (H*S = 32768)
        int s = (int)(row & (S_ - 1));
        float ww = w[b * S_ + s];
        vfloat4 x = __builtin_nontemporal_load(&in[i]);  // streamed, never reused
        x *= ww;
        __builtin_nontemporal_store(x, &out[i]);         // streamed, never reused
    }
}

extern "C" void kernel_launch(void* const* d_in, const int* in_sizes, int n_in,
                              void* d_out, int out_size, void* d_ws, size_t ws_size,
                              hipStream_t stream) {
    const float* scores = (const float*)d_in[0];
    const int*   ids    = (const int*)  d_in[1];
    const float* embW   = (const float*)d_in[2];
    const float* lnvw   = (const float*)d_in[3];
    const float* lnvb   = (const float*)d_in[4];
    const float* pW1    = (const float*)d_in[5];
    const float* pb1    = (const float*)d_in[6];
    const float* pW2    = (const float*)d_in[7];
    const float* pb2    = (const float*)d_in[8];
    const float* lncw   = (const float*)d_in[9];
    const float* lncb   = (const float*)d_in[10];
    const float* fW1    = (const float*)d_in[11];
    const float* fb1    = (const float*)d_in[12];
    const float* fW2    = (const float*)d_in[13];
    const float* fb2    = (const float*)d_in[14];
    const float* fW3    = (const float*)d_in[15];
    const float* fb3    = (const float*)d_in[16];

    int*   counts = (int*)d_ws;
    float* wout   = (float*)((char*)d_ws + CTX_ * sizeof(int));

    count_kernel<<<1, 1024, 0, stream>>>(ids, counts);
    token_mlp_kernel<<<NBLK_, 512, 0, stream>>>(
        ids, counts, embW, lnvw, lnvb, pW1, pb1, pW2, pb2,
        lncw, lncb, fW1, fb1, fW2, fb2, fW3, fb3, wout);

    long total4 = (long)B_ * H_ * S_ * S_ / 4;   // 33,554,432 float4s
    scale_kernel<<<2048, 256, 0, stream>>>(
        (const vfloat4*)scores, wout, (vfloat4*)d_out, total4);
}